// Round 2
// baseline (15483.763 us; speedup 1.0000x reference)
//
#include <hip/hip_runtime.h>
#include <cstdint>
#include <cstddef>

#define LSEQ 512
#define BATCH 64
#define DIM 256
#define HID 256
#define NTAG 11

// ---------------- init: zero group-barrier counters ----------------
__global__ void init_ctr(unsigned int* __restrict__ ctr) {
    for (int i = threadIdx.x; i < 1024; i += 256) ctr[i] = 0u;
}

// ---------------- input GEMM (+embedding gather, +bias) ----------------
// Gin layout: [dir][t_local][b>>2][n(1024)][b&3]  (so the recurrent kernel's
// group of 4 batch elems reads fully-contiguous float4s)
__global__ void __launch_bounds__(256) gemm_in(
    const int* __restrict__ sent, const float* __restrict__ emb,
    const float* __restrict__ Wf, const float* __restrict__ bf,
    const float* __restrict__ Wb, const float* __restrict__ bb,
    float* __restrict__ Gin, int t0, int CT)
{
    const int mt = blockIdx.x, nt = blockIdx.y, dir = blockIdx.z;
    const float* __restrict__ W    = dir ? Wb : Wf;
    const float* __restrict__ bias = dir ? bb : bf;
    const int tid = threadIdx.x;
    const int tx = tid & 15, ty = tid >> 4;

    __shared__ float As[128][36];   // [m][k] pad to 36 for bank spread + 16B rows
    __shared__ float Bs[128][36];   // [n][k]

    // staging row pointers (4 float4 loads per thread per k-iter)
    const float* arow[4];
    const float* brow[4];
#pragma unroll
    for (int j = 0; j < 4; j++) {
        int v  = j * 256 + tid;        // 0..1023  (f4 index)
        int mi = v >> 3;               // 0..127
        int m_g = mt * 128 + mi;
        int b = m_g & 63, tl = m_g >> 6;
        int tg = t0 + tl;
        int tt = dir ? (LSEQ - 1 - tg) : tg;
        int tok = sent[b * LSEQ + tt];
        arow[j] = emb + (size_t)tok * DIM;
        brow[j] = W + (size_t)(nt * 128 + mi) * DIM;
    }

    float acc[8][8];
#pragma unroll
    for (int i = 0; i < 8; i++)
#pragma unroll
        for (int j = 0; j < 8; j++) acc[i][j] = 0.f;

    for (int ki = 0; ki < 8; ki++) {
        const int k0 = ki * 32;
        __syncthreads();
#pragma unroll
        for (int j = 0; j < 4; j++) {
            int v  = j * 256 + tid;
            int mi = v >> 3, k4 = v & 7;
            float4 av = *(const float4*)(arow[j] + k0 + k4 * 4);
            float4 bv = *(const float4*)(brow[j] + k0 + k4 * 4);
            *(float4*)&As[mi][k4 * 4] = av;
            *(float4*)&Bs[mi][k4 * 4] = bv;
        }
        __syncthreads();
#pragma unroll
        for (int k = 0; k < 32; k++) {
            float a[8], bv[8];
#pragma unroll
            for (int i = 0; i < 8; i++) a[i] = As[ty + 16 * i][k];
#pragma unroll
            for (int j = 0; j < 8; j++) bv[j] = Bs[tx + 16 * j][k];
#pragma unroll
            for (int i = 0; i < 8; i++)
#pragma unroll
                for (int j = 0; j < 8; j++) acc[i][j] = fmaf(a[i], bv[j], acc[i][j]);
        }
    }
#pragma unroll
    for (int i = 0; i < 8; i++) {
        int m_g = mt * 128 + ty + 16 * i;
        int b = m_g & 63, tl = m_g >> 6;
        size_t base = ((size_t)(dir * CT + tl) * 16 + (b >> 2)) * 4096 + (b & 3);
#pragma unroll
        for (int j = 0; j < 8; j++) {
            int n = nt * 128 + tx + 16 * j;
            Gin[base + (size_t)n * 4] = acc[i][j] + bias[n];
        }
    }
}

// ---------------- persistent bidirectional LSTM recurrence ----------------
// 256 WGs = 32 groups x 8 WGs. group g: dir = g>>4, batch [4*(g&15), +4).
// WG w in group owns hidden slice j in [32w, 32w+32) -> 128 W_hh rows, held in
// 128 VGPRs (32 float4/thread, thread covers half of K). c in registers.
// h exchanged via AGENT-SCOPE ATOMIC loads/stores on a global ping-pong buffer
// (coherence-point accesses; no reliance on wbl2/inv fence codegen) + a
// per-group acq_rel counter barrier.
// __launch_bounds__(256,2): VGPR<=256 + 10KB LDS => >=2 resident blocks/CU =>
// all 256 blocks of a REGULAR launch are co-resident under any packing (no
// cooperative launch needed; spin barrier cannot deadlock).
__global__ void __launch_bounds__(256, 2) lstm_rec(
    const float* __restrict__ Gin,
    const float* __restrict__ Whh_f, const float* __restrict__ Whh_b,
    const float* __restrict__ h0, const float* __restrict__ c0,
    float* __restrict__ hs, float* __restrict__ hbuf, float* __restrict__ cbuf,
    unsigned int* __restrict__ ctr, int t0, int CT)
{
    const int wg = blockIdx.x;
    const int g  = wg >> 3, w = wg & 7;
    const int dir   = g >> 4;
    const int bbase = (g & 15) << 2;
    const int jbase = w << 5;
    const int tid = threadIdx.x;
    const int r = tid & 127, s = tid >> 7;          // row 0..127, k-half
    const int q = r >> 5, jj = r & 31;
    const int row_g = (q << 8) + jbase + jj;        // global gate-row in [0,1024)
    const float* __restrict__ Whh = dir ? Whh_b : Whh_f;

    float4 wreg[32];
    {
        const float4* wp = (const float4*)(Whh + (size_t)row_g * HID + s * 128);
#pragma unroll
        for (int i = 0; i < 32; i++) wreg[i] = wp[i];
    }

    __shared__ float4 Hl[4][64];       // staged h for 4 batch
    __shared__ float4 part[128][2];    // k-half partials, .x..w = b0..b3
    __shared__ float4 gsum[128];       // gate preacts

    const int jj2 = tid & 31, b2 = (tid >> 5) & 3; // phase-B ownership (tid<128)
    float c_reg = 0.f;
    if (tid < 128) {
        size_t cidx = ((size_t)(dir * BATCH) + bbase + b2) * HID + jbase + jj2;
        c_reg = (t0 == 0) ? c0[cidx] : cbuf[cidx];
    }

    unsigned int* myctr = ctr + g * 32;
    const int stage_b = tid >> 6, stage_k = tid & 63;

    for (int t = t0; t < t0 + CT; t++) {
        // stage h(t-1) for our 4 batch elems (agent-scope atomic loads: read
        // the coherence point, immune to stale L1/L2)
        const float* hsrc = (t == 0)
            ? (h0 + (size_t)dir * BATCH * HID)
            : (hbuf + ((size_t)((t - 1) & 1) * 2 + dir) * BATCH * HID);
        {
            const float* hp = hsrc + (size_t)(bbase + stage_b) * HID + stage_k * 4;
            float4 hvv;
            hvv.x = __hip_atomic_load(hp + 0, __ATOMIC_RELAXED, __HIP_MEMORY_SCOPE_AGENT);
            hvv.y = __hip_atomic_load(hp + 1, __ATOMIC_RELAXED, __HIP_MEMORY_SCOPE_AGENT);
            hvv.z = __hip_atomic_load(hp + 2, __ATOMIC_RELAXED, __HIP_MEMORY_SCOPE_AGENT);
            hvv.w = __hip_atomic_load(hp + 3, __ATOMIC_RELAXED, __HIP_MEMORY_SCOPE_AGENT);
            Hl[stage_b][stage_k] = hvv;
        }

        // prefetch input-projection gates (consumed after inner loop)
        float4 gv = make_float4(0.f, 0.f, 0.f, 0.f);
        if (tid < 128)
            gv = ((const float4*)Gin)[((size_t)(dir * CT + (t - t0)) * 16
                                       + (bbase >> 2)) * 1024 + row_g];
        __syncthreads();

        float ax = 0.f, ay = 0.f, az = 0.f, aw = 0.f;
#pragma unroll
        for (int i = 0; i < 32; i++) {
            const int k4 = (s << 5) + i;
            const float4 wv = wreg[i];
            float4 hv;
            hv = Hl[0][k4];
            ax = fmaf(wv.x, hv.x, ax); ax = fmaf(wv.y, hv.y, ax);
            ax = fmaf(wv.z, hv.z, ax); ax = fmaf(wv.w, hv.w, ax);
            hv = Hl[1][k4];
            ay = fmaf(wv.x, hv.x, ay); ay = fmaf(wv.y, hv.y, ay);
            ay = fmaf(wv.z, hv.z, ay); ay = fmaf(wv.w, hv.w, ay);
            hv = Hl[2][k4];
            az = fmaf(wv.x, hv.x, az); az = fmaf(wv.y, hv.y, az);
            az = fmaf(wv.z, hv.z, az); az = fmaf(wv.w, hv.w, az);
            hv = Hl[3][k4];
            aw = fmaf(wv.x, hv.x, aw); aw = fmaf(wv.y, hv.y, aw);
            aw = fmaf(wv.z, hv.z, aw); aw = fmaf(wv.w, hv.w, aw);
        }
        part[r][s] = make_float4(ax, ay, az, aw);
        __syncthreads();

        if (tid < 128) {
            float4 p0 = part[tid][0], p1 = part[tid][1];
            float4 tot;
            tot.x = p0.x + p1.x + gv.x;
            tot.y = p0.y + p1.y + gv.y;
            tot.z = p0.z + p1.z + gv.z;
            tot.w = p0.w + p1.w + gv.w;
            gsum[tid] = tot;
        }
        __syncthreads();

        if (tid < 128) {
            const float gi_ = ((const float*)&gsum[      jj2])[b2];
            const float gf_ = ((const float*)&gsum[ 32 + jj2])[b2];
            const float gg_ = ((const float*)&gsum[ 64 + jj2])[b2];
            const float go_ = ((const float*)&gsum[ 96 + jj2])[b2];
            const float ig = 1.f / (1.f + expf(-gi_));
            const float fg = 1.f / (1.f + expf(-gf_));
            const float og = 1.f / (1.f + expf(-go_));
            c_reg = fg * c_reg + ig * tanhf(gg_);
            const float hv = og * tanhf(c_reg);
            const int t_orig = dir ? (LSEQ - 1 - t) : t;
            hs[((size_t)(dir * LSEQ + t_orig) * BATCH + bbase + b2) * HID + jbase + jj2] = hv;
            __hip_atomic_store(
                &hbuf[(((size_t)(t & 1) * 2 + dir) * BATCH + bbase + b2) * HID + jbase + jj2],
                hv, __ATOMIC_RELAXED, __HIP_MEMORY_SCOPE_AGENT);
        }
        // group barrier: fence (drain our atomic stores to coherence point) ->
        // block barrier -> acq_rel counter add by tid0 -> acquire spin -> barrier
        __threadfence();
        __syncthreads();
        if (tid == 0) {
            __hip_atomic_fetch_add(myctr, 1u, __ATOMIC_ACQ_REL, __HIP_MEMORY_SCOPE_AGENT);
            const unsigned int target = 8u * (unsigned int)(t + 1);
            while (__hip_atomic_load(myctr, __ATOMIC_ACQUIRE, __HIP_MEMORY_SCOPE_AGENT) < target) {
                __builtin_amdgcn_s_sleep(1);
            }
        }
        __syncthreads();
    }
    if (tid < 128) {
        size_t cidx = ((size_t)(dir * BATCH) + bbase + b2) * HID + jbase + jj2;
        cbuf[cidx] = c_reg;
    }
}

// ---------------- output projection: logits[b][t][11] ----------------
__global__ void __launch_bounds__(256) logits_k(
    const float* __restrict__ hs, const float* __restrict__ Wout,
    const float* __restrict__ bout, float* __restrict__ logits)
{
    const int tid = threadIdx.x;
    const int rt = tid >> 4, tg = tid & 15;
    __shared__ float hrow[16][516];
    __shared__ float Wl[NTAG][516];
    const int rbase = blockIdx.x * 16;

#pragma unroll
    for (int i = 0; i < 8; i++) {
        int u  = tid + i * 256;        // 0..2047
        int rr = u >> 7, c4 = u & 127;
        int r_g = rbase + rr;
        int b = r_g >> 9, t = r_g & 511;
        int d = (c4 >= 64) ? 1 : 0, k4 = c4 & 63;
        float4 hv = ((const float4*)hs)[(((size_t)d * LSEQ + t) * BATCH + b) * 64 + k4];
        *(float4*)&hrow[rr][c4 * 4] = hv;
    }
    for (int u = tid; u < NTAG * 128; u += 256) {
        int row = u >> 7, c4 = u & 127;
        float4 wv = ((const float4*)Wout)[(size_t)row * 128 + c4];
        *(float4*)&Wl[row][c4 * 4] = wv;
    }
    __syncthreads();

    if (tg < NTAG) {
        const float4* hp = (const float4*)&hrow[rt][0];
        const float4* wp = (const float4*)&Wl[tg][0];
        float acc = 0.f;
#pragma unroll 4
        for (int k = 0; k < 128; k++) {
            float4 h = hp[k], ww = wp[k];
            acc = fmaf(h.x, ww.x, acc); acc = fmaf(h.y, ww.y, acc);
            acc = fmaf(h.z, ww.z, acc); acc = fmaf(h.w, ww.w, acc);
        }
        int r_g = rbase + rt;
        logits[(size_t)r_g * NTAG + tg] = acc + bout[tg];
    }
}

// ---------------- Viterbi (one wave per batch element) ----------------
__global__ void __launch_bounds__(64) viterbi_k(
    const float* __restrict__ logits, const float* __restrict__ trans,
    float* __restrict__ out)
{
    const int b = blockIdx.x, lane = threadIdx.x;
    __shared__ float lgl[LSEQ * NTAG];
    __shared__ unsigned char bp[LSEQ][16];
    __shared__ float pathf[LSEQ];

    {
        const float4* src = (const float4*)(logits + (size_t)b * LSEQ * NTAG);
        float4* dst = (float4*)lgl;
        for (int u = lane; u < (LSEQ * NTAG) / 4; u += 64) dst[u] = src[u];
    }
    float tcol[NTAG];
    if (lane < NTAG) {
#pragma unroll
        for (int i = 0; i < NTAG; i++) tcol[i] = trans[i * NTAG + lane];
    }
    __syncthreads();

    float v = (lane < NTAG) ? lgl[lane] : -1e30f;
    for (int t = 1; t < LSEQ; t++) {
        float best = -1e30f; int bi = 0;
#pragma unroll
        for (int i = 0; i < NTAG; i++) {
            float vi = __shfl(v, i, 64) + tcol[i];
            if (vi > best) { best = vi; bi = i; }   // strict > == first-max (argmax semantics)
        }
        if (lane < NTAG) {
            v = lgl[t * NTAG + lane] + best;
            bp[t][lane] = (unsigned char)bi;
        }
    }
    float bestv = -1e30f; int bestj = 0;
#pragma unroll
    for (int j = 0; j < NTAG; j++) {
        float vj = __shfl(v, j, 64);
        if (vj > bestv) { bestv = vj; bestj = j; }
    }
    if (lane == 0) {
        out[b] = bestv;
        int st = bestj;
        pathf[LSEQ - 1] = (float)st;
        for (int t = LSEQ - 1; t >= 1; t--) { st = bp[t][st]; pathf[t - 1] = (float)st; }
    }
    __syncthreads();
    for (int t = lane; t < LSEQ; t += 64)
        out[BATCH + (size_t)b * LSEQ + t] = pathf[t];
}

// ---------------- host ----------------
extern "C" void kernel_launch(void* const* d_in, const int* in_sizes, int n_in,
                              void* d_out, int out_size, void* d_ws, size_t ws_size,
                              hipStream_t stream)
{
    (void)in_sizes; (void)n_in; (void)out_size;
    const int*   sent  = (const int*)  d_in[0];
    const float* emb   = (const float*)d_in[1];
    const float* Wihf  = (const float*)d_in[2];
    const float* Whhf  = (const float*)d_in[3];
    const float* bf    = (const float*)d_in[4];
    const float* Wihb  = (const float*)d_in[5];
    const float* Whhb  = (const float*)d_in[6];
    const float* bb    = (const float*)d_in[7];
    const float* Wout  = (const float*)d_in[8];
    const float* bout  = (const float*)d_in[9];
    const float* trans = (const float*)d_in[10];
    const float* h0    = (const float*)d_in[11];
    const float* c0    = (const float*)d_in[12];
    float* out = (float*)d_out;

    // ws layout (floats): Gin[CT*131072] | hs[16777216] | hbuf[65536] |
    //                     cbuf[32768] | logits[360448] | ctr[1024 u32]
    const size_t fixed = 16777216ull + 65536ull + 32768ull + 360448ull + 1024ull;
    int CT = LSEQ;
    while (CT > 8 && ((size_t)CT * 131072ull + fixed) * 4ull > ws_size) CT >>= 1;

    float* ws = (float*)d_ws;
    size_t off = 0;
    float* Gin  = ws + off; off += (size_t)CT * 131072ull;
    float* hs   = ws + off; off += 16777216ull;
    float* hbuf = ws + off; off += 65536ull;
    float* cbuf = ws + off; off += 32768ull;
    float* lgts = ws + off; off += 360448ull;
    unsigned int* ctr = (unsigned int*)(ws + off);

    hipLaunchKernelGGL(init_ctr, dim3(1), dim3(256), 0, stream, ctr);

    const int nch = LSEQ / CT;
    for (int c = 0; c < nch; c++) {
        int t0 = c * CT;
        hipLaunchKernelGGL(gemm_in, dim3(CT / 2, 8, 2), dim3(256), 0, stream,
                           sent, emb, Wihf, bf, Wihb, bb, Gin, t0, CT);
        hipLaunchKernelGGL(lstm_rec, dim3(256), dim3(256), 0, stream,
                           Gin, Whhf, Whhb, h0, c0, hs, hbuf, cbuf, ctr, t0, CT);
    }
    hipLaunchKernelGGL(logits_k, dim3((BATCH * LSEQ) / 16), dim3(256), 0, stream,
                       hs, Wout, bout, lgts);
    hipLaunchKernelGGL(viterbi_k, dim3(BATCH), dim3(64), 0, stream,
                       lgts, trans, out);
}

// Round 4
// 3844.566 us; speedup vs baseline: 4.0274x; 4.0274x over previous
//
#include <hip/hip_runtime.h>
#include <cstdint>
#include <cstddef>
#include <cstring>

#define LSEQ 512
#define BATCH 64
#define DIM 256
#define HID 256
#define NTAG 11

// ---------------- init: zero group-barrier counters ----------------
__global__ void init_ctr(unsigned int* __restrict__ ctr) {
    for (int i = threadIdx.x; i < 1024; i += 256) ctr[i] = 0u;
}

// ---------------- input GEMM (+embedding gather, +bias) ----------------
// Gin layout: [dir][t_local][b>>2][n(1024)][b&3]
__global__ void __launch_bounds__(256) gemm_in(
    const int* __restrict__ sent, const float* __restrict__ emb,
    const float* __restrict__ Wf, const float* __restrict__ bf,
    const float* __restrict__ Wb, const float* __restrict__ bb,
    float* __restrict__ Gin, int t0, int CT)
{
    const int mt = blockIdx.x, nt = blockIdx.y, dir = blockIdx.z;
    const float* __restrict__ W    = dir ? Wb : Wf;
    const float* __restrict__ bias = dir ? bb : bf;
    const int tid = threadIdx.x;
    const int tx = tid & 15, ty = tid >> 4;

    __shared__ float As[128][36];
    __shared__ float Bs[128][36];

    const float* arow[4];
    const float* brow[4];
#pragma unroll
    for (int j = 0; j < 4; j++) {
        int v  = j * 256 + tid;
        int mi = v >> 3;
        int m_g = mt * 128 + mi;
        int b = m_g & 63, tl = m_g >> 6;
        int tg = t0 + tl;
        int tt = dir ? (LSEQ - 1 - tg) : tg;
        int tok = sent[b * LSEQ + tt];
        arow[j] = emb + (size_t)tok * DIM;
        brow[j] = W + (size_t)(nt * 128 + mi) * DIM;
    }

    float acc[8][8];
#pragma unroll
    for (int i = 0; i < 8; i++)
#pragma unroll
        for (int j = 0; j < 8; j++) acc[i][j] = 0.f;

    for (int ki = 0; ki < 8; ki++) {
        const int k0 = ki * 32;
        __syncthreads();
#pragma unroll
        for (int j = 0; j < 4; j++) {
            int v  = j * 256 + tid;
            int mi = v >> 3, k4 = v & 7;
            float4 av = *(const float4*)(arow[j] + k0 + k4 * 4);
            float4 bv = *(const float4*)(brow[j] + k0 + k4 * 4);
            *(float4*)&As[mi][k4 * 4] = av;
            *(float4*)&Bs[mi][k4 * 4] = bv;
        }
        __syncthreads();
#pragma unroll
        for (int k = 0; k < 32; k++) {
            float a[8], bv[8];
#pragma unroll
            for (int i = 0; i < 8; i++) a[i] = As[ty + 16 * i][k];
#pragma unroll
            for (int j = 0; j < 8; j++) bv[j] = Bs[tx + 16 * j][k];
#pragma unroll
            for (int i = 0; i < 8; i++)
#pragma unroll
                for (int j = 0; j < 8; j++) acc[i][j] = fmaf(a[i], bv[j], acc[i][j]);
        }
    }
#pragma unroll
    for (int i = 0; i < 8; i++) {
        int m_g = mt * 128 + ty + 16 * i;
        int b = m_g & 63, tl = m_g >> 6;
        size_t base = ((size_t)(dir * CT + tl) * 16 + (b >> 2)) * 4096 + (b & 3);
#pragma unroll
        for (int j = 0; j < 8; j++) {
            int n = nt * 128 + tx + 16 * j;
            Gin[base + (size_t)n * 4] = acc[i][j] + bias[n];
        }
    }
}

// ---------------- persistent bidirectional LSTM recurrence ----------------
// 256 WGs = 32 groups x 8 WGs. Group g = {wg : wg & 31 == g} (stride-32
// members => same XCD under blockIdx%8 round-robin — perf only).
// Group g: dir=g>>4, batch [4*(g&15),+4). Member w owns hidden j in
// [32w,32w+32) -> 128 W_hh rows in 128 VGPRs.
//
// Cross-WG protocol (NO fences, NO cache maintenance):
//   - cross-WG payload (hbuf) + counter use agent-scope atomics only =>
//     bypass non-coherent L1/L2 to the MALL (coherence point).
//   - __syncthreads() before tid0's add emits s_waitcnt vmcnt(0) per wave,
//     so every wave's h-stores are acked at MALL before the counter add.
//   - relaxed spin; post-spin __syncthreads broadcasts readiness.
// __launch_bounds__(256,1): VGPR cap 512 so wreg[32] (128 VGPRs) stays
// register-resident (at (256,2) the compiler sank the loads into the loop).
__global__ void __launch_bounds__(256, 1) lstm_rec(
    const float* __restrict__ Gin,
    const float* __restrict__ Whh_f, const float* __restrict__ Whh_b,
    const float* __restrict__ h0, const float* __restrict__ c0,
    float* __restrict__ hs, float* __restrict__ hbuf, float* __restrict__ cbuf,
    unsigned int* __restrict__ ctr, int t0, int CT)
{
    const int wg = blockIdx.x;
    const int w = wg >> 5, g = wg & 31;   // same-XCD group members
    const int dir   = g >> 4;
    const int bbase = (g & 15) << 2;
    const int jbase = w << 5;
    const int tid = threadIdx.x;
    const int r = tid & 127, s = tid >> 7;          // row 0..127, k-half
    const int q = r >> 5, jj = r & 31;
    const int row_g = (q << 8) + jbase + jj;        // global gate-row in [0,1024)
    const float* __restrict__ Whh = dir ? Whh_b : Whh_f;

    float4 wreg[32];
    {
        const float4* wp = (const float4*)(Whh + (size_t)row_g * HID + s * 128);
#pragma unroll
        for (int i = 0; i < 32; i++) wreg[i] = wp[i];
    }

    __shared__ float4 Hl[4][64];          // staged h for 4 batch (f4 broadcast reads)
    __shared__ float  part_f[128][9];     // [row][half*4+batch], stride 9 = conflict-free
    __shared__ float  gsum_f[4 * 132];    // [gate][batch*33+jj], stride 33 = conflict-free

    const int jj2 = tid & 31, b2 = (tid >> 5) & 3; // phase-B ownership (tid<128)
    float c_reg = 0.f;
    if (tid < 128) {
        size_t cidx = ((size_t)(dir * BATCH) + bbase + b2) * HID + jbase + jj2;
        c_reg = (t0 == 0) ? c0[cidx] : cbuf[cidx];
    }

    unsigned int* myctr = ctr + g * 32;
    const int stage_b = tid >> 6, stage_k = tid & 63;

    // Gin base in FLOAT4 units: elem (dir,tl,bg,n,bl) has float idx
    // ((dir*CT+tl)*16+bg)*4096 + n*4 + bl  ==> float4 idx ((dir*CT+tl)*16+bg)*1024 + n
    const size_t gin_wg_base = (size_t)(dir * CT) * 16384 + (size_t)(bbase >> 2) * 1024;
    const float4* __restrict__ Gin4 = (const float4*)Gin;

    // prefetch Gin for first step (t_local = 0)
    float4 gv = make_float4(0.f, 0.f, 0.f, 0.f);
    if (tid < 128)
        gv = Gin4[gin_wg_base + row_g];

    for (int t = t0; t < t0 + CT; t++) {
        // ---- stage h(t-1): agent-scope (cache-bypassing) 8B atomic loads ----
        const float* hsrc = (t == 0)
            ? (h0 + (size_t)dir * BATCH * HID)
            : (hbuf + ((size_t)((t - 1) & 1) * 2 + dir) * BATCH * HID);
        {
            const float* hp = hsrc + (size_t)(bbase + stage_b) * HID + stage_k * 4;
            unsigned long long u0 = __hip_atomic_load((const unsigned long long*)hp,
                                     __ATOMIC_RELAXED, __HIP_MEMORY_SCOPE_AGENT);
            unsigned long long u1 = __hip_atomic_load((const unsigned long long*)(hp + 2),
                                     __ATOMIC_RELAXED, __HIP_MEMORY_SCOPE_AGENT);
            float4 hvv;
            memcpy(&hvv.x, &u0, 8);
            memcpy(&hvv.z, &u1, 8);
            Hl[stage_b][stage_k] = hvv;
        }
        __syncthreads();

        // ---- prefetch Gin for t+1 (hides HBM latency behind FMA+reduce) ----
        float4 gvn = make_float4(0.f, 0.f, 0.f, 0.f);
        {
            int tln = (t + 1 < t0 + CT) ? (t + 1 - t0) : (CT - 1);
            if (tid < 128)
                gvn = Gin4[gin_wg_base + (size_t)tln * 16384 + row_g];
        }

        // ---- inner GEMV: 4 batches x (128 rows x half-K) ----
        float ax = 0.f, ay = 0.f, az = 0.f, aw = 0.f;
#pragma unroll
        for (int i = 0; i < 32; i++) {
            const int k4 = (s << 5) + i;
            const float4 wv = wreg[i];
            float4 hv;
            hv = Hl[0][k4];
            ax = fmaf(wv.x, hv.x, ax); ax = fmaf(wv.y, hv.y, ax);
            ax = fmaf(wv.z, hv.z, ax); ax = fmaf(wv.w, hv.w, ax);
            hv = Hl[1][k4];
            ay = fmaf(wv.x, hv.x, ay); ay = fmaf(wv.y, hv.y, ay);
            ay = fmaf(wv.z, hv.z, ay); ay = fmaf(wv.w, hv.w, ay);
            hv = Hl[2][k4];
            az = fmaf(wv.x, hv.x, az); az = fmaf(wv.y, hv.y, az);
            az = fmaf(wv.z, hv.z, az); az = fmaf(wv.w, hv.w, az);
            hv = Hl[3][k4];
            aw = fmaf(wv.x, hv.x, aw); aw = fmaf(wv.y, hv.y, aw);
            aw = fmaf(wv.z, hv.z, aw); aw = fmaf(wv.w, hv.w, aw);
        }
        part_f[r][s * 4 + 0] = ax;
        part_f[r][s * 4 + 1] = ay;
        part_f[r][s * 4 + 2] = az;
        part_f[r][s * 4 + 3] = aw;
        __syncthreads();

        // ---- reduce halves + add Gin, transpose into gsum ----
        if (tid < 128) {
#pragma unroll
            for (int b = 0; b < 4; b++) {
                float tot = part_f[tid][b] + part_f[tid][4 + b]
                          + ((const float*)&gv)[b];
                gsum_f[q * 132 + b * 33 + jj] = tot;
            }
        }
        __syncthreads();

        // ---- activations + h/c update + stores ----
        if (tid < 128) {
            const float gi_ = gsum_f[0 * 132 + b2 * 33 + jj2];
            const float gf_ = gsum_f[1 * 132 + b2 * 33 + jj2];
            const float gg_ = gsum_f[2 * 132 + b2 * 33 + jj2];
            const float go_ = gsum_f[3 * 132 + b2 * 33 + jj2];
            const float ig = 1.f / (1.f + expf(-gi_));
            const float fg = 1.f / (1.f + expf(-gf_));
            const float og = 1.f / (1.f + expf(-go_));
            c_reg = fg * c_reg + ig * tanhf(gg_);
            const float hv = og * tanhf(c_reg);
            const int t_orig = dir ? (LSEQ - 1 - t) : t;
            __hip_atomic_store(
                &hs[((size_t)(dir * LSEQ + t_orig) * BATCH + bbase + b2) * HID + jbase + jj2],
                hv, __ATOMIC_RELAXED, __HIP_MEMORY_SCOPE_AGENT);
            __hip_atomic_store(
                &hbuf[(((size_t)(t & 1) * 2 + dir) * BATCH + bbase + b2) * HID + jbase + jj2],
                hv, __ATOMIC_RELAXED, __HIP_MEMORY_SCOPE_AGENT);
        }
        gv = gvn;

        // ---- group barrier: drain (syncthreads) -> relaxed add -> relaxed spin ----
        __syncthreads();   // per-wave vmcnt(0) before s_barrier => h at MALL
        if (tid == 0) {
            __hip_atomic_fetch_add(myctr, 1u, __ATOMIC_RELAXED, __HIP_MEMORY_SCOPE_AGENT);
            const unsigned int target = 8u * (unsigned int)(t + 1);
            while (__hip_atomic_load(myctr, __ATOMIC_RELAXED, __HIP_MEMORY_SCOPE_AGENT) < target) {
                __builtin_amdgcn_s_sleep(1);
            }
        }
        __syncthreads();
    }
    if (tid < 128) {
        size_t cidx = ((size_t)(dir * BATCH) + bbase + b2) * HID + jbase + jj2;
        cbuf[cidx] = c_reg;
    }
}

// ---------------- output projection: logits[b][t][11] ----------------
__global__ void __launch_bounds__(256) logits_k(
    const float* __restrict__ hs, const float* __restrict__ Wout,
    const float* __restrict__ bout, float* __restrict__ logits)
{
    const int tid = threadIdx.x;
    const int rt = tid >> 4, tg = tid & 15;
    __shared__ float hrow[16][516];
    __shared__ float Wl[NTAG][516];
    const int rbase = blockIdx.x * 16;

#pragma unroll
    for (int i = 0; i < 8; i++) {
        int u  = tid + i * 256;
        int rr = u >> 7, c4 = u & 127;
        int r_g = rbase + rr;
        int b = r_g >> 9, t = r_g & 511;
        int d = (c4 >= 64) ? 1 : 0, k4 = c4 & 63;
        float4 hv = ((const float4*)hs)[(((size_t)d * LSEQ + t) * BATCH + b) * 64 + k4];
        *(float4*)&hrow[rr][c4 * 4] = hv;
    }
    for (int u = tid; u < NTAG * 128; u += 256) {
        int row = u >> 7, c4 = u & 127;
        float4 wv = ((const float4*)Wout)[(size_t)row * 128 + c4];
        *(float4*)&Wl[row][c4 * 4] = wv;
    }
    __syncthreads();

    if (tg < NTAG) {
        const float4* hp = (const float4*)&hrow[rt][0];
        const float4* wp = (const float4*)&Wl[tg][0];
        float acc = 0.f;
#pragma unroll 4
        for (int k = 0; k < 128; k++) {
            float4 h = hp[k], ww = wp[k];
            acc = fmaf(h.x, ww.x, acc); acc = fmaf(h.y, ww.y, acc);
            acc = fmaf(h.z, ww.z, acc); acc = fmaf(h.w, ww.w, acc);
        }
        int r_g = rbase + rt;
        logits[(size_t)r_g * NTAG + tg] = acc + bout[tg];
    }
}

// ---------------- Viterbi (one wave per batch element) ----------------
__global__ void __launch_bounds__(64) viterbi_k(
    const float* __restrict__ logits, const float* __restrict__ trans,
    float* __restrict__ out)
{
    const int b = blockIdx.x, lane = threadIdx.x;
    __shared__ float lgl[LSEQ * NTAG];
    __shared__ unsigned char bp[LSEQ][16];
    __shared__ float pathf[LSEQ];

    {
        const float4* src = (const float4*)(logits + (size_t)b * LSEQ * NTAG);
        float4* dst = (float4*)lgl;
        for (int u = lane; u < (LSEQ * NTAG) / 4; u += 64) dst[u] = src[u];
    }
    float tcol[NTAG];
    if (lane < NTAG) {
#pragma unroll
        for (int i = 0; i < NTAG; i++) tcol[i] = trans[i * NTAG + lane];
    }
    __syncthreads();

    float v = (lane < NTAG) ? lgl[lane] : -1e30f;
    for (int t = 1; t < LSEQ; t++) {
        float best = -1e30f; int bi = 0;
#pragma unroll
        for (int i = 0; i < NTAG; i++) {
            float vi = __shfl(v, i, 64) + tcol[i];
            if (vi > best) { best = vi; bi = i; }   // strict > == first-max
        }
        if (lane < NTAG) {
            v = lgl[t * NTAG + lane] + best;
            bp[t][lane] = (unsigned char)bi;
        }
    }
    float bestv = -1e30f; int bestj = 0;
#pragma unroll
    for (int j = 0; j < NTAG; j++) {
        float vj = __shfl(v, j, 64);
        if (vj > bestv) { bestv = vj; bestj = j; }
    }
    if (lane == 0) {
        out[b] = bestv;
        int st = bestj;
        pathf[LSEQ - 1] = (float)st;
        for (int t = LSEQ - 1; t >= 1; t--) { st = bp[t][st]; pathf[t - 1] = (float)st; }
    }
    __syncthreads();
    for (int t = lane; t < LSEQ; t += 64)
        out[BATCH + (size_t)b * LSEQ + t] = pathf[t];
}

// ---------------- host ----------------
extern "C" void kernel_launch(void* const* d_in, const int* in_sizes, int n_in,
                              void* d_out, int out_size, void* d_ws, size_t ws_size,
                              hipStream_t stream)
{
    (void)in_sizes; (void)n_in; (void)out_size;
    const int*   sent  = (const int*)  d_in[0];
    const float* emb   = (const float*)d_in[1];
    const float* Wihf  = (const float*)d_in[2];
    const float* Whhf  = (const float*)d_in[3];
    const float* bf    = (const float*)d_in[4];
    const float* Wihb  = (const float*)d_in[5];
    const float* Whhb  = (const float*)d_in[6];
    const float* bb    = (const float*)d_in[7];
    const float* Wout  = (const float*)d_in[8];
    const float* bout  = (const float*)d_in[9];
    const float* trans = (const float*)d_in[10];
    const float* h0    = (const float*)d_in[11];
    const float* c0    = (const float*)d_in[12];
    float* out = (float*)d_out;

    const size_t fixed = 16777216ull + 65536ull + 32768ull + 360448ull + 1024ull;
    int CT = LSEQ;
    while (CT > 8 && ((size_t)CT * 131072ull + fixed) * 4ull > ws_size) CT >>= 1;

    float* ws = (float*)d_ws;
    size_t off = 0;
    float* Gin  = ws + off; off += (size_t)CT * 131072ull;
    float* hs   = ws + off; off += 16777216ull;
    float* hbuf = ws + off; off += 65536ull;
    float* cbuf = ws + off; off += 32768ull;
    float* lgts = ws + off; off += 360448ull;
    unsigned int* ctr = (unsigned int*)(ws + off);

    hipLaunchKernelGGL(init_ctr, dim3(1), dim3(256), 0, stream, ctr);

    const int nch = LSEQ / CT;
    for (int c = 0; c < nch; c++) {
        int t0 = c * CT;
        hipLaunchKernelGGL(gemm_in, dim3(CT / 2, 8, 2), dim3(256), 0, stream,
                           sent, emb, Wihf, bf, Wihb, bb, Gin, t0, CT);
        hipLaunchKernelGGL(lstm_rec, dim3(256), dim3(256), 0, stream,
                           Gin, Whhf, Whhb, h0, c0, hs, hbuf, cbuf, ctr, t0, CT);
    }
    hipLaunchKernelGGL(logits_k, dim3((BATCH * LSEQ) / 16), dim3(256), 0, stream,
                       hs, Wout, bout, lgts);
    hipLaunchKernelGGL(viterbi_k, dim3(BATCH), dim3(64), 0, stream,
                       lgts, trans, out);
}